// Round 6
// baseline (243.609 us; speedup 1.0000x reference)
//
#include <hip/hip_runtime.h>

// Problem: B=2, H=32, S=8192, D=128, T=512, fp32.
// out = (updated_k, updated_v) concatenated flat: each B*H*S*D = 67,108,864 floats.

#define S_LEN 8192
#define T_LEN 512
#define D_DIM 128
#define BH    64            // B*H
#define ELEMS_PER_TENSOR (BH * S_LEN * D_DIM)      // 67,108,864 floats
#define VECS_PER_BH      (S_LEN * (D_DIM / 4))     // 262,144 float4s per bh slice
#define NEW_VECS_PER_BH  (T_LEN * (D_DIM / 4))     // 16,384 float4s per bh slice

// Native clang vector type — __builtin_nontemporal_* requires this.
typedef float f4_t __attribute__((ext_vector_type(4)));

// --- single fused kernel -------------------------------------------------
// grid = (1024, 2), block = 256.  2048 blocks = exactly 8 blocks/CU.
//   blockIdx.y: 0 = K, 1 = V  (1 read + 1 write stream per thread).
//   blockIdx.x: (s,d4) chunk — block covers 8 consecutive seq rows × 32 d4.
// Each thread owns a fixed (s,d4); t = lmap[s&7] and the new-vs-cache branch
// are hoisted out of the bh loop (uniform per thread). Inner loop walks all
// 64 bh slices in an explicit 8-deep load-batch / store-batch pipeline so 8
// nontemporal dwordx4 loads are in flight before the first store issues.
__global__ __launch_bounds__(256) void ssc_fused(
    const f4_t* __restrict__ ck, const f4_t* __restrict__ cv,
    const f4_t* __restrict__ nk, const f4_t* __restrict__ nv,
    const void* __restrict__ pos,
    f4_t* __restrict__ ok, f4_t* __restrict__ ov) {

    __shared__ int lmap[8];
    const int ltid = threadIdx.x;
    const int s0   = blockIdx.x * 8;           // first seq row of this block

    if (ltid < 8) lmap[ltid] = -1;
    __syncthreads();

    // positions may arrive as int32 or int64; detect by range-checking the
    // first two 8-byte reads (int32 read as int64 misparses element 1).
    {
        const long long* p64 = (const long long*)pos;
        const int*       p32 = (const int*)pos;
        long long a = p64[0], b = p64[1];
        bool is64 = (a >= 0) && (a < S_LEN) && (b >= 0) && (b < S_LEN) && (a != b);
        #pragma unroll
        for (int j = ltid; j < T_LEN; j += 256) {
            int p = is64 ? (int)p64[j] : p32[j];
            unsigned r = (unsigned)(p - s0);
            if (r < 8u) lmap[r] = j;
        }
    }
    __syncthreads();

    const int tid = blockIdx.x * 256 + ltid;   // 0 .. 262143
    const int d4  = tid & 31;                  // 32 float4s per row
    const int s   = tid >> 5;                  // 0 .. 8191
    const int t   = lmap[s & 7];

    // pick tensor (grid-uniform)
    const f4_t* csrc = blockIdx.y ? cv : ck;
    const f4_t* nsrc = blockIdx.y ? nv : nk;
    f4_t*       odst = blockIdx.y ? ov : ok;

    const int dstOff = s * 32 + d4;            // vec index within a bh slice

    const f4_t* src;
    int sstride;
    if (t >= 0) { src = nsrc + (t * 32 + d4); sstride = NEW_VECS_PER_BH; }
    else        { src = csrc + dstOff;        sstride = VECS_PER_BH; }
    f4_t* dst = odst + dstOff;

    #pragma unroll
    for (int ii = 0; ii < BH; ii += 8) {
        f4_t r[8];
        #pragma unroll
        for (int j = 0; j < 8; ++j)
            r[j] = __builtin_nontemporal_load(src + (long)(ii + j) * sstride);
        #pragma unroll
        for (int j = 0; j < 8; ++j)
            __builtin_nontemporal_store(r[j], dst + (long)(ii + j) * VECS_PER_BH);
    }
}

extern "C" void kernel_launch(void* const* d_in, const int* in_sizes, int n_in,
                              void* d_out, int out_size, void* d_ws, size_t ws_size,
                              hipStream_t stream) {
    const f4_t* ck = (const f4_t*)d_in[0];
    const f4_t* cv = (const f4_t*)d_in[1];
    const f4_t* nk = (const f4_t*)d_in[2];
    const f4_t* nv = (const f4_t*)d_in[3];
    const void* pos = d_in[4];

    float* out = (float*)d_out;
    f4_t* ok = (f4_t*)out;
    f4_t* ov = (f4_t*)(out + ELEMS_PER_TENSOR);

    ssc_fused<<<dim3(1024, 2), 256, 0, stream>>>(ck, cv, nk, nv, pos, ok, ov);
}